// Round 1
// baseline (3959.182 us; speedup 1.0000x reference)
//
#include <hip/hip_runtime.h>
#include <math.h>

// Problem constants
constexpr int Bc = 2, Sc = 2048, Dc = 2048, Hc = 16, HDc = 128;
constexpr int Mc = Bc * Sc;              // 4096 rows
constexpr float SCALE = 0.08838834764831845f;  // 1/sqrt(128)

// ---------------- GEMM: out = X[M,D] @ W[D,D]^T + bias ----------------
// MODE 0: scatter output to [B,H,S,HD] (for q/k/v)
// MODE 1: plain row-major [M,D]       (for final projection)
constexpr int BM = 128, BN = 128, BK = 16;

template <int MODE>
__global__ __launch_bounds__(256) void gemm_nt(
    const float* __restrict__ X, const float* __restrict__ W,
    const float* __restrict__ bias, float* __restrict__ out) {
  __shared__ float As[BK][BM + 4];   // pitch 132: staging writes 2-way (free)
  __shared__ float Bs[BK][BN + 4];
  const int t = threadIdx.x;
  const int tm = t >> 4, tn = t & 15;
  const int m0 = blockIdx.y * BM, n0 = blockIdx.x * BN;

  float acc[8][8];
#pragma unroll
  for (int r = 0; r < 8; ++r)
#pragma unroll
    for (int c = 0; c < 8; ++c) acc[r][c] = 0.f;

  for (int k0 = 0; k0 < Dc; k0 += BK) {
#pragma unroll
    for (int i = 0; i < 2; ++i) {
      int f = t + 256 * i;            // 0..511 float4 slots
      int row = f >> 2, kc = (f & 3) * 4;
      float4 a = *reinterpret_cast<const float4*>(
          &X[(size_t)(m0 + row) * Dc + k0 + kc]);
      As[kc + 0][row] = a.x; As[kc + 1][row] = a.y;
      As[kc + 2][row] = a.z; As[kc + 3][row] = a.w;
      float4 b = *reinterpret_cast<const float4*>(
          &W[(size_t)(n0 + row) * Dc + k0 + kc]);
      Bs[kc + 0][row] = b.x; Bs[kc + 1][row] = b.y;
      Bs[kc + 2][row] = b.z; Bs[kc + 3][row] = b.w;
    }
    __syncthreads();
#pragma unroll
    for (int kk = 0; kk < BK; ++kk) {
      float4 a0 = *reinterpret_cast<const float4*>(&As[kk][tm * 8]);
      float4 a1 = *reinterpret_cast<const float4*>(&As[kk][tm * 8 + 4]);
      float4 b0 = *reinterpret_cast<const float4*>(&Bs[kk][tn * 8]);
      float4 b1 = *reinterpret_cast<const float4*>(&Bs[kk][tn * 8 + 4]);
      float av[8] = {a0.x, a0.y, a0.z, a0.w, a1.x, a1.y, a1.z, a1.w};
      float bv[8] = {b0.x, b0.y, b0.z, b0.w, b1.x, b1.y, b1.z, b1.w};
#pragma unroll
      for (int r = 0; r < 8; ++r)
#pragma unroll
        for (int c = 0; c < 8; ++c) acc[r][c] += av[r] * bv[c];
    }
    __syncthreads();
  }

#pragma unroll
  for (int r = 0; r < 8; ++r) {
    int row = m0 + tm * 8 + r;
#pragma unroll
    for (int c4 = 0; c4 < 2; ++c4) {
      int colb = n0 + tn * 8 + c4 * 4;
      float4 bb = *reinterpret_cast<const float4*>(&bias[colb]);
      float4 o;
      o.x = acc[r][c4 * 4 + 0] + bb.x;
      o.y = acc[r][c4 * 4 + 1] + bb.y;
      o.z = acc[r][c4 * 4 + 2] + bb.z;
      o.w = acc[r][c4 * 4 + 3] + bb.w;
      if (MODE == 0) {
        int b = row >> 11, s = row & (Sc - 1);
        int h = colb >> 7, d = colb & (HDc - 1);
        *reinterpret_cast<float4*>(
            &out[(size_t)((b * Hc + h) * Sc + s) * HDc + d]) = o;
      } else {
        *reinterpret_cast<float4*>(&out[(size_t)row * Dc + colb]) = o;
      }
    }
  }
}

// ---------------- Flash-style fp32 attention ----------------
// grid: (S/QT, B*H), block 256.  Q,K,V in [B,H,S,HD].
constexpr int QT = 32, KT = 64;

__global__ __launch_bounds__(256) void attn_fwd(
    const float* __restrict__ Q, const float* __restrict__ K,
    const float* __restrict__ V, const float* __restrict__ mask,
    float* __restrict__ out) {
  __shared__ float Qs[QT][HDc + 4];       // 16.9 KB
  __shared__ float KVs[KT][HDc + 4];      // 33.8 KB (K then V)
  __shared__ float Ps[QT][KT + 4];        //  8.7 KB
  const int t = threadIdx.x;
  const int tq = t >> 3;                  // q-row within tile (0..31)
  const int tj = t & 7;                   // lane within row-group
  const int bh = blockIdx.y;              // b*H + h
  const int bq = bh >> 4;                 // batch
  const int q0 = blockIdx.x * QT;
  const float* Qp = Q + (size_t)bh * Sc * HDc;
  const float* Kp = K + (size_t)bh * Sc * HDc;
  const float* Vp = V + (size_t)bh * Sc * HDc;

  // stage Q tile once
#pragma unroll
  for (int i = 0; i < 4; ++i) {
    int f = t + 256 * i;                  // 0..1023 float4
    int row = f >> 5, d4 = (f & 31) * 4;
    *reinterpret_cast<float4*>(&Qs[row][d4]) =
        *reinterpret_cast<const float4*>(&Qp[(size_t)(q0 + row) * HDc + d4]);
  }

  float m = -INFINITY, l = 0.f;
  float4 o[4];
#pragma unroll
  for (int mm = 0; mm < 4; ++mm) o[mm] = make_float4(0.f, 0.f, 0.f, 0.f);

  for (int kt = 0; kt < Sc / KT; ++kt) {
    const int k0 = kt * KT;
    // stage K tile
#pragma unroll
    for (int i = 0; i < 8; ++i) {
      int f = t + 256 * i;                // 0..2047 float4
      int row = f >> 5, d4 = (f & 31) * 4;
      *reinterpret_cast<float4*>(&KVs[row][d4]) =
          *reinterpret_cast<const float4*>(&Kp[(size_t)(k0 + row) * HDc + d4]);
    }
    __syncthreads();

    // scores: thread owns S[tq][tj + 8j], j=0..7 (stride-8 interleave ->
    // conflict-free b128 K reads, broadcast Q reads)
    float sv[8];
#pragma unroll
    for (int j = 0; j < 8; ++j) sv[j] = 0.f;
#pragma unroll
    for (int d4 = 0; d4 < HDc / 4; ++d4) {
      float4 q4 = *reinterpret_cast<const float4*>(&Qs[tq][d4 * 4]);
#pragma unroll
      for (int j = 0; j < 8; ++j) {
        float4 k4 = *reinterpret_cast<const float4*>(&KVs[tj + 8 * j][d4 * 4]);
        sv[j] += q4.x * k4.x + q4.y * k4.y + q4.z * k4.z + q4.w * k4.w;
      }
    }
    const float* mrow = mask + ((size_t)bq * Sc + q0 + tq) * Sc + k0;
    float tmax = -INFINITY;
#pragma unroll
    for (int j = 0; j < 8; ++j) {
      sv[j] = sv[j] * SCALE + mrow[tj + 8 * j];
      tmax = fmaxf(tmax, sv[j]);
    }
#pragma unroll
    for (int off = 1; off < 8; off <<= 1)
      tmax = fmaxf(tmax, __shfl_xor(tmax, off, 64));
    const float mn = fmaxf(m, tmax);
    const float alpha = __expf(m - mn);   // first iter: exp(-inf)=0
    float psum = 0.f;
#pragma unroll
    for (int j = 0; j < 8; ++j) {
      float p = __expf(sv[j] - mn);
      Ps[tq][tj + 8 * j] = p;
      psum += p;
    }
#pragma unroll
    for (int off = 1; off < 8; off <<= 1) psum += __shfl_xor(psum, off, 64);
    l = l * alpha + psum;
    m = mn;
#pragma unroll
    for (int mm = 0; mm < 4; ++mm) {
      o[mm].x *= alpha; o[mm].y *= alpha;
      o[mm].z *= alpha; o[mm].w *= alpha;
    }
    __syncthreads();                      // done reading K, Ps published

    // stage V tile (reuse KVs)
#pragma unroll
    for (int i = 0; i < 8; ++i) {
      int f = t + 256 * i;
      int row = f >> 5, d4 = (f & 31) * 4;
      *reinterpret_cast<float4*>(&KVs[row][d4]) =
          *reinterpret_cast<const float4*>(&Vp[(size_t)(k0 + row) * HDc + d4]);
    }
    __syncthreads();

    // o[tq][d] += sum_kk P[tq][kk] * V[kk][d]; thread owns d4 = tj + 8*mm
#pragma unroll
    for (int kk = 0; kk < KT; ++kk) {
      float p = Ps[tq][kk];               // 8-lane broadcast
#pragma unroll
      for (int mm = 0; mm < 4; ++mm) {
        float4 v4 =
            *reinterpret_cast<const float4*>(&KVs[kk][(tj + 8 * mm) * 4]);
        o[mm].x += p * v4.x; o[mm].y += p * v4.y;
        o[mm].z += p * v4.z; o[mm].w += p * v4.w;
      }
    }
    __syncthreads();                      // before next K overwrite
  }

  const float rl = 1.f / l;
  const int h = bh & (Hc - 1);
  const int row = q0 + tq;
#pragma unroll
  for (int mm = 0; mm < 4; ++mm) {
    float4 ov = o[mm];
    ov.x *= rl; ov.y *= rl; ov.z *= rl; ov.w *= rl;
    *reinterpret_cast<float4*>(
        &out[((size_t)bq * Sc + row) * Dc + h * HDc + (tj + 8 * mm) * 4]) = ov;
  }
}

// ---------------- launch ----------------
extern "C" void kernel_launch(void* const* d_in, const int* in_sizes, int n_in,
                              void* d_out, int out_size, void* d_ws,
                              size_t ws_size, hipStream_t stream) {
  const float* hs   = (const float*)d_in[0];
  const float* mask = (const float*)d_in[1];
  const float* Wq   = (const float*)d_in[2];
  const float* bq   = (const float*)d_in[3];
  const float* Wk   = (const float*)d_in[4];
  const float* bk   = (const float*)d_in[5];
  const float* Wv   = (const float*)d_in[6];
  const float* bv   = (const float*)d_in[7];
  const float* Wo   = (const float*)d_in[8];
  const float* bo   = (const float*)d_in[9];
  float* out = (float*)d_out;
  float* ws  = (float*)d_ws;

  const size_t SZ = (size_t)Mc * Dc;      // 8.4M floats per tensor
  float* qb = ws;
  float* kb = ws + SZ;
  float* vb = ws + 2 * SZ;
  float* ab = ws + 3 * SZ;                // attention output [B,S,D]

  dim3 blk(256);
  dim3 gg(Dc / BN, Mc / BM);              // (16, 32)
  gemm_nt<0><<<gg, blk, 0, stream>>>(hs, Wq, bq, qb);
  gemm_nt<0><<<gg, blk, 0, stream>>>(hs, Wk, bk, kb);
  gemm_nt<0><<<gg, blk, 0, stream>>>(hs, Wv, bv, vb);
  attn_fwd<<<dim3(Sc / QT, Bc * Hc), blk, 0, stream>>>(qb, kb, vb, mask, ab);
  gemm_nt<1><<<gg, blk, 0, stream>>>(ab, Wo, bo, out);
}

// Round 2
// 416.972 us; speedup vs baseline: 9.4951x; 9.4951x over previous
//
#include <hip/hip_runtime.h>
#include <hip/hip_bf16.h>
#include <math.h>

typedef unsigned short u16;
typedef unsigned int u32;
typedef __attribute__((ext_vector_type(8))) short bf16x8;   // 8 bf16 = 4 VGPRs
typedef __attribute__((ext_vector_type(4))) float f32x4;

constexpr int Bc = 2, Sc = 2048, Dc = 2048, Hc = 16, HDc = 128;
constexpr int Mc = Bc * Sc;                     // 4096
constexpr float SCALE = 0.08838834764831845f;   // 1/sqrt(128)

__device__ inline u16 f2bf(float f) {
  __hip_bfloat16 h = __float2bfloat16(f);
  return __builtin_bit_cast(u16, h);
}

typedef const __attribute__((address_space(1))) u32 glb_u32;
typedef __attribute__((address_space(3))) u32 lds_u32;
__device__ inline void gload16(const void* g, void* l) {
  // async global->LDS, 16B per lane; LDS dest must be wave-uniform base (+lane*16 implicit)
  __builtin_amdgcn_global_load_lds((glb_u32*)g, (lds_u32*)l, 16, 0, 0);
}

// ---------------- fp32 -> bf16 convert (hidden + 4 weights) ----------------
__global__ __launch_bounds__(256) void cvt5(
    const float* __restrict__ s0, u16* __restrict__ d0, int n0,
    const float* __restrict__ s1, u16* __restrict__ d1, int n1,
    const float* __restrict__ s2, u16* __restrict__ d2, int n2,
    const float* __restrict__ s3, u16* __restrict__ d3, int n3,
    const float* __restrict__ s4, u16* __restrict__ d4, int n4) {
  int i = blockIdx.x * 256 + threadIdx.x;   // float4 index
  const float* s; u16* d;
  if (i < n0) { s = s0; d = d0; }
  else { i -= n0;
    if (i < n1) { s = s1; d = d1; }
    else { i -= n1;
      if (i < n2) { s = s2; d = d2; }
      else { i -= n2;
        if (i < n3) { s = s3; d = d3; }
        else { i -= n3;
          if (i >= n4) return;
          s = s4; d = d4; } } } }
  float4 v = reinterpret_cast<const float4*>(s)[i];
  ushort4 o;
  o.x = f2bf(v.x); o.y = f2bf(v.y); o.z = f2bf(v.z); o.w = f2bf(v.w);
  reinterpret_cast<ushort4*>(d)[i] = o;
}

// ---------------- bf16 MFMA GEMM: C[M,N] = A[M,K] * W[N,K]^T + bias --------
// MODE 0: bf16 scatter to [B,H,S,HD]; MODE 1: fp32 row-major [M,N] to d_out
constexpr int GBM = 128, GBN = 128, GBK = 64;

template <int MODE>
__global__ __launch_bounds__(256) void gemm_bf16(
    const u16* __restrict__ A, const u16* __restrict__ W,
    const float* __restrict__ bias, void* __restrict__ outp) {
  __shared__ u16 As[GBM * GBK];   // [row][64k] linear, 16 KB
  __shared__ u16 Bs[GBN * GBK];
  char* Asb = (char*)As;
  char* Bsb = (char*)Bs;
  const int t = threadIdx.x;
  const int w = t >> 6, lane = t & 63, g = lane >> 4, c = lane & 15;
  const int wm = w >> 1, wn = w & 1;
  const int m0 = blockIdx.y * GBM, n0 = blockIdx.x * GBN;

  f32x4 acc[4][4];
#pragma unroll
  for (int m = 0; m < 4; ++m)
#pragma unroll
    for (int n = 0; n < 4; ++n) acc[m][n] = 0.f;

  for (int k0 = 0; k0 < Dc; k0 += GBK) {
    // stage A,B tiles: 1024 16B-units each; unit u: row=u>>3, cu=u&7
#pragma unroll
    for (int i = 0; i < 4; ++i) {
      int u = i * 256 + t;
      int row = u >> 3, cu = u & 7;
      int ub = i * 256 + (t & 192);           // wave-uniform unit base
      gload16(A + (size_t)(m0 + row) * Dc + k0 + cu * 8, Asb + ub * 16);
      gload16(W + (size_t)(n0 + row) * Dc + k0 + cu * 8, Bsb + ub * 16);
    }
    __syncthreads();
#pragma unroll
    for (int s = 0; s < 2; ++s) {
      bf16x8 af[4], bfv[4];
#pragma unroll
      for (int m = 0; m < 4; ++m)
        af[m] = *(const bf16x8*)(Asb + (wm * 64 + m * 16 + c) * 128 + s * 64 + g * 16);
#pragma unroll
      for (int n = 0; n < 4; ++n)
        bfv[n] = *(const bf16x8*)(Bsb + (wn * 64 + n * 16 + c) * 128 + s * 64 + g * 16);
#pragma unroll
      for (int m = 0; m < 4; ++m)
#pragma unroll
        for (int n = 0; n < 4; ++n)
          acc[m][n] = __builtin_amdgcn_mfma_f32_16x16x32_bf16(af[m], bfv[n], acc[m][n], 0, 0, 0);
    }
    __syncthreads();
  }

#pragma unroll
  for (int m = 0; m < 4; ++m)
#pragma unroll
    for (int n = 0; n < 4; ++n) {
      int col = n0 + wn * 64 + n * 16 + c;
      float bv = bias[col];
#pragma unroll
      for (int r = 0; r < 4; ++r) {
        int row = m0 + wm * 64 + m * 16 + g * 4 + r;
        float v = acc[m][n][r] + bv;
        if (MODE == 0) {
          int b = row >> 11, si = row & (Sc - 1);
          int h = col >> 7, d = col & (HDc - 1);
          ((u16*)outp)[((size_t)((b * Hc + h) * Sc + si)) * HDc + d] = f2bf(v);
        } else {
          ((float*)outp)[(size_t)row * Dc + col] = v;
        }
      }
    }
}

// ---------------- bf16 MFMA flash attention ----------------
// grid (S/64, B*H), 256 thr = 4 waves; wave owns 16 q-rows. K,Vt XOR-swizzled.
__global__ __launch_bounds__(256) void attn_mfma(
    const u16* __restrict__ Q, const u16* __restrict__ K,
    const u16* __restrict__ V, const float* __restrict__ mask,
    u16* __restrict__ outb) {
  __shared__ u16 Ks[64 * 128];    // 16 KB; unit(row,cu16): stored (cu&8)|((cu^row)&7)
  __shared__ u16 Vt[128 * 64];    // 16 KB; V transposed [d][k]; cu8 ^ (row&7)
  __shared__ u16 Ps[4][16 * 64];  // 8 KB; per-wave P [q][k]; cu8 ^ (row&7)
  char* Ksb = (char*)Ks;
  char* Vtb = (char*)Vt;
  const int t = threadIdx.x, w = t >> 6, lane = t & 63, g = lane >> 4, c = lane & 15;
  const int bh = blockIdx.y, bq = bh >> 4, h = bh & 15;
  const int q0 = blockIdx.x * 64;
  const u16* Qp = Q + ((size_t)bh << 18);
  const u16* Kp = K + ((size_t)bh << 18);
  const u16* Vp = V + ((size_t)bh << 18);
  char* Psb = (char*)Ps[w];

  // Q fragments in registers: A[row=c][k=d], 4 d-steps of 32
  bf16x8 qf[4];
  {
    int qr = q0 + w * 16 + c;
#pragma unroll
    for (int d0 = 0; d0 < 4; ++d0)
      qf[d0] = *(const bf16x8*)(Qp + (size_t)qr * HDc + d0 * 32 + g * 8);
  }

  f32x4 po[8];                       // O^T acc: d = m*16+g*4+r, q = c
#pragma unroll
  for (int m = 0; m < 8; ++m) po[m] = 0.f;
  float mrow[4], lrow[4];
#pragma unroll
  for (int r = 0; r < 4; ++r) { mrow[r] = -INFINITY; lrow[r] = 0.f; }

  const float* mbase = mask + ((size_t)bq * Sc + q0 + w * 16) * Sc;

  for (int kt = 0; kt < Sc / 64; ++kt) {
    const int k0 = kt * 64;
    // stage K tile (swizzled 16B units)
#pragma unroll
    for (int i = 0; i < 4; ++i) {
      int u = i * 256 + t, row = u >> 4, cu = u & 15;
      float4 kv = *(const float4*)(Kp + (size_t)(k0 + row) * HDc + cu * 8);
      int scu = (cu & 8) | ((cu ^ row) & 7);
      *(float4*)(Ksb + row * 256 + scu * 16) = kv;
    }
    // stage V transposed: thread handles key-pair kp, 8 d's
#pragma unroll
    for (int i = 0; i < 2; ++i) {
      int a2 = i * 256 + t, kp = a2 & 31, dc = a2 >> 5;   // dc 0..15
      float4 v0 = *(const float4*)(Vp + (size_t)(k0 + 2 * kp) * HDc + dc * 8);
      float4 v1 = *(const float4*)(Vp + (size_t)(k0 + 2 * kp + 1) * HDc + dc * 8);
      const u16* a0 = (const u16*)&v0;
      const u16* a1 = (const u16*)&v1;
#pragma unroll
      for (int j = 0; j < 8; ++j) {
        int d = dc * 8 + j;
        u32 val = (u32)a0[j] | ((u32)a1[j] << 16);
        int scu = (kp >> 2) ^ (d & 7);
        *(u32*)(Vtb + d * 128 + scu * 16 + (kp & 3) * 4) = val;
      }
    }
    __syncthreads();

    // QK^T: S[q 16][k 64] per wave
    f32x4 sfr[4];
#pragma unroll
    for (int n = 0; n < 4; ++n) sfr[n] = 0.f;
#pragma unroll
    for (int ds = 0; ds < 4; ++ds)
#pragma unroll
      for (int n = 0; n < 4; ++n) {
        int row = n * 16 + c;
        int cu = ds * 4 + g;
        int scu = (cu & 8) | ((cu ^ row) & 7);
        bf16x8 kf = *(const bf16x8*)(Ksb + row * 256 + scu * 16);
        sfr[n] = __builtin_amdgcn_mfma_f32_16x16x32_bf16(qf[ds], kf, sfr[n], 0, 0, 0);
      }

    // online softmax (fp32); rows q = g*4+r across 16 c-lanes
    float al[4];
#pragma unroll
    for (int r = 0; r < 4; ++r) {
      const float* mrp = mbase + (size_t)(g * 4 + r) * Sc + k0;
      float sv[4];
#pragma unroll
      for (int n = 0; n < 4; ++n) sv[n] = sfr[n][r] * SCALE + mrp[n * 16 + c];
      float tm = fmaxf(fmaxf(sv[0], sv[1]), fmaxf(sv[2], sv[3]));
#pragma unroll
      for (int off = 1; off < 16; off <<= 1) tm = fmaxf(tm, __shfl_xor(tm, off, 64));
      float mn = fmaxf(mrow[r], tm);
      al[r] = __expf(mrow[r] - mn);
      float ps = 0.f;
      int qr = g * 4 + r;
#pragma unroll
      for (int n = 0; n < 4; ++n) {
        float p = __expf(sv[n] - mn);
        ps += p;
        int col = n * 16 + c;
        int scu = (col >> 3) ^ (qr & 7);
        *(u16*)(Psb + qr * 128 + scu * 16 + (col & 7) * 2) = f2bf(p);
      }
#pragma unroll
      for (int off = 1; off < 16; off <<= 1) ps += __shfl_xor(ps, off, 64);
      lrow[r] = lrow[r] * al[r] + ps;
      mrow[r] = mn;
    }
    // broadcast alpha from row-holder lanes to q=c lanes
    float av0 = __shfl(al[0], (c >> 2) * 16, 64);
    float av1 = __shfl(al[1], (c >> 2) * 16, 64);
    float av2 = __shfl(al[2], (c >> 2) * 16, 64);
    float av3 = __shfl(al[3], (c >> 2) * 16, 64);
    float x0 = ((c & 3) == 1) ? av1 : av0;
    float x1 = ((c & 3) == 3) ? av3 : av2;
    float alq = ((c & 3) >= 2) ? x1 : x0;
#pragma unroll
    for (int m = 0; m < 8; ++m) po[m] *= alq;

    // PV: O^T = V^T * P^T
#pragma unroll
    for (int s2 = 0; s2 < 2; ++s2) {
      int cuP = s2 * 4 + g;
      bf16x8 pf = *(const bf16x8*)(Psb + c * 128 + (cuP ^ (c & 7)) * 16);
#pragma unroll
      for (int m = 0; m < 8; ++m) {
        int rowv = m * 16 + c;
        int cuv = s2 * 4 + g;
        bf16x8 vf = *(const bf16x8*)(Vtb + rowv * 128 + ((cuv ^ (rowv & 7)) & 7) * 16);
        po[m] = __builtin_amdgcn_mfma_f32_16x16x32_bf16(vf, pf, po[m], 0, 0, 0);
      }
    }
    __syncthreads();
  }

  // finalize: divide by l (per q=c), write bf16 [B,S,D]
  float rv[4];
#pragma unroll
  for (int r = 0; r < 4; ++r) rv[r] = 1.0f / lrow[r];
  float bv0 = __shfl(rv[0], (c >> 2) * 16, 64);
  float bv1 = __shfl(rv[1], (c >> 2) * 16, 64);
  float bv2 = __shfl(rv[2], (c >> 2) * 16, 64);
  float bv3 = __shfl(rv[3], (c >> 2) * 16, 64);
  float y0 = ((c & 3) == 1) ? bv1 : bv0;
  float y1 = ((c & 3) == 3) ? bv3 : bv2;
  float rlq = ((c & 3) >= 2) ? y1 : y0;
  int qg = q0 + w * 16 + c;
#pragma unroll
  for (int m = 0; m < 8; ++m)
#pragma unroll
    for (int r = 0; r < 4; ++r) {
      int d = m * 16 + g * 4 + r;
      outb[((size_t)(bq * Sc + qg)) * Dc + h * HDc + d] = f2bf(po[m][r] * rlq);
    }
}

// ---------------- launch ----------------
extern "C" void kernel_launch(void* const* d_in, const int* in_sizes, int n_in,
                              void* d_out, int out_size, void* d_ws,
                              size_t ws_size, hipStream_t stream) {
  const float* hs   = (const float*)d_in[0];
  const float* mask = (const float*)d_in[1];
  const float* Wq   = (const float*)d_in[2];
  const float* bqp  = (const float*)d_in[3];
  const float* Wk   = (const float*)d_in[4];
  const float* bkp  = (const float*)d_in[5];
  const float* Wv   = (const float*)d_in[6];
  const float* bvp  = (const float*)d_in[7];
  const float* Wo   = (const float*)d_in[8];
  const float* bop  = (const float*)d_in[9];

  u16* Xb  = (u16*)d_ws;                 // [4096][2048]
  u16* Wqb = Xb + (size_t)Mc * Dc;       // 8388608
  u16* Wkb = Wqb + (size_t)Dc * Dc / 1;  // weights are 2048*2048
  u16* Wvb = Wkb + (size_t)Dc * Dc;
  u16* Wob = Wvb + (size_t)Dc * Dc;
  u16* qb  = Wob + (size_t)Dc * Dc;      // [B,H,S,HD] bf16
  u16* kb  = qb + (size_t)Mc * Dc;
  u16* vb  = kb + (size_t)Mc * Dc;
  u16* ab  = vb + (size_t)Mc * Dc;       // [B,S,D] bf16

  const int nh4 = Mc * Dc / 4;           // 2097152
  const int nw4 = Dc * Dc / 4;           // 1048576
  cvt5<<<dim3((nh4 + 4 * nw4) / 256), dim3(256), 0, stream>>>(
      hs, Xb, nh4, Wq, Wqb, nw4, Wk, Wkb, nw4, Wv, Wvb, nw4, Wo, Wob, nw4);

  dim3 blk(256);
  dim3 gg(Dc / GBN, Mc / GBM);           // (16, 32)
  gemm_bf16<0><<<gg, blk, 0, stream>>>(Xb, Wqb, bqp, qb);
  gemm_bf16<0><<<gg, blk, 0, stream>>>(Xb, Wkb, bkp, kb);
  gemm_bf16<0><<<gg, blk, 0, stream>>>(Xb, Wvb, bvp, vb);
  attn_mfma<<<dim3(Sc / 64, Bc * Hc), blk, 0, stream>>>(qb, kb, vb, mask, ab);
  gemm_bf16<1><<<gg, blk, 0, stream>>>(ab, Wob, bop, d_out);
}

// Round 3
// 354.112 us; speedup vs baseline: 11.1806x; 1.1775x over previous
//
#include <hip/hip_runtime.h>
#include <hip/hip_bf16.h>
#include <math.h>

typedef unsigned short u16;
typedef unsigned int u32;
typedef __attribute__((ext_vector_type(8))) short bf16x8;   // 8 bf16 = 4 VGPRs
typedef __attribute__((ext_vector_type(4))) float f32x4;

constexpr int Bc = 2, Sc = 2048, Dc = 2048, Hc = 16, HDc = 128;
constexpr int Mc = Bc * Sc;                     // 4096
constexpr float SCALE = 0.08838834764831845f;   // 1/sqrt(128)

__device__ inline u16 f2bf(float f) {
  __hip_bfloat16 h = __float2bfloat16(f);
  return __builtin_bit_cast(u16, h);
}

typedef const __attribute__((address_space(1))) u32 glb_u32;
typedef __attribute__((address_space(3))) u32 lds_u32;
__device__ inline void gload16(const void* g, void* l) {
  // async global->LDS, 16B/lane; LDS dest is wave-uniform base + lane*16
  __builtin_amdgcn_global_load_lds((glb_u32*)g, (lds_u32*)l, 16, 0, 0);
}

// ---------------- fp32 -> bf16 convert (hidden + 4 weights) ----------------
__global__ __launch_bounds__(256) void cvt5(
    const float* __restrict__ s0, u16* __restrict__ d0, int n0,
    const float* __restrict__ s1, u16* __restrict__ d1, int n1,
    const float* __restrict__ s2, u16* __restrict__ d2, int n2,
    const float* __restrict__ s3, u16* __restrict__ d3, int n3,
    const float* __restrict__ s4, u16* __restrict__ d4, int n4) {
  int i = blockIdx.x * 256 + threadIdx.x;   // float4 index
  const float* s; u16* d;
  if (i < n0) { s = s0; d = d0; }
  else { i -= n0;
    if (i < n1) { s = s1; d = d1; }
    else { i -= n1;
      if (i < n2) { s = s2; d = d2; }
      else { i -= n2;
        if (i < n3) { s = s3; d = d3; }
        else { i -= n3;
          if (i >= n4) return;
          s = s4; d = d4; } } } }
  float4 v = reinterpret_cast<const float4*>(s)[i];
  ushort4 o;
  o.x = f2bf(v.x); o.y = f2bf(v.y); o.z = f2bf(v.z); o.w = f2bf(v.w);
  reinterpret_cast<ushort4*>(d)[i] = o;
}

// ---------------- bf16 MFMA GEMM: C[M,N] = A[M,K] * W[N,K]^T + bias --------
// MODE 0: bf16 scatter to [B,H,S,HD], output scaled by `scale`
// MODE 1: fp32 row-major [M,N] to d_out
// MODE 2: bf16 transposed scatter to [B,H,HD,S]  (for V^T)
constexpr int GBM = 128, GBN = 128, GBK = 64;

template <int MODE>
__global__ __launch_bounds__(256) void gemm_bf16(
    const u16* __restrict__ A, const u16* __restrict__ W,
    const float* __restrict__ bias, void* __restrict__ outp, float scale) {
  __shared__ u16 smem[17408];     // As[8192] | Bs[8192]; epilogue CT[128*136]
  u16* As = smem;
  u16* Bs = smem + 8192;
  char* Asb = (char*)As;
  char* Bsb = (char*)Bs;
  const int t = threadIdx.x;
  const int w = t >> 6, lane = t & 63, g = lane >> 4, c = lane & 15;
  const int wm = w >> 1, wn = w & 1;
  const int m0 = blockIdx.y * GBM, n0 = blockIdx.x * GBN;

  f32x4 acc[4][4];
#pragma unroll
  for (int m = 0; m < 4; ++m)
#pragma unroll
    for (int n = 0; n < 4; ++n) acc[m][n] = 0.f;

  for (int k0 = 0; k0 < Dc; k0 += GBK) {
#pragma unroll
    for (int i = 0; i < 4; ++i) {
      int u = i * 256 + t;
      int row = u >> 3, cu = u & 7;
      int ub = i * 256 + (t & 192);           // wave-uniform unit base
      gload16(A + (size_t)(m0 + row) * Dc + k0 + cu * 8, Asb + ub * 16);
      gload16(W + (size_t)(n0 + row) * Dc + k0 + cu * 8, Bsb + ub * 16);
    }
    __syncthreads();
#pragma unroll
    for (int s = 0; s < 2; ++s) {
      bf16x8 af[4], bfv[4];
#pragma unroll
      for (int m = 0; m < 4; ++m)
        af[m] = *(const bf16x8*)(Asb + (wm * 64 + m * 16 + c) * 128 + s * 64 + g * 16);
#pragma unroll
      for (int n = 0; n < 4; ++n)
        bfv[n] = *(const bf16x8*)(Bsb + (wn * 64 + n * 16 + c) * 128 + s * 64 + g * 16);
#pragma unroll
      for (int m = 0; m < 4; ++m)
#pragma unroll
        for (int n = 0; n < 4; ++n)
          acc[m][n] = __builtin_amdgcn_mfma_f32_16x16x32_bf16(af[m], bfv[n], acc[m][n], 0, 0, 0);
    }
    __syncthreads();
  }

  if (MODE == 2) {
    // transpose through LDS, then coalesced bf16 writes to [B,H,HD,S]
    u16* CT = smem;                           // [128 d][136 pitch] u16
    __syncthreads();
#pragma unroll
    for (int m = 0; m < 4; ++m)
#pragma unroll
      for (int n = 0; n < 4; ++n) {
        int lcol = wn * 64 + n * 16 + c;      // d (local)
        float bv = bias[n0 + lcol];
#pragma unroll
        for (int r = 0; r < 4; ++r) {
          int lrow = wm * 64 + m * 16 + g * 4 + r;   // s (local)
          CT[lcol * 136 + lrow] = f2bf(acc[m][n][r] + bv);
        }
      }
    __syncthreads();
    const int b = m0 >> 11, h = n0 >> 7, s0 = m0 & (Sc - 1);
    u16* op = (u16*)outp;
#pragma unroll
    for (int i = 0; i < 8; ++i) {
      int u = i * 256 + t;
      int d = u >> 4, su = u & 15;
      float4 v4 = *(const float4*)(&CT[d * 136 + su * 8]);
      *(float4*)(&op[((size_t)((b * Hc + h) * HDc) + d) * Sc + s0 + su * 8]) = v4;
    }
    return;
  }

#pragma unroll
  for (int m = 0; m < 4; ++m)
#pragma unroll
    for (int n = 0; n < 4; ++n) {
      int col = n0 + wn * 64 + n * 16 + c;
      float bv = bias[col];
#pragma unroll
      for (int r = 0; r < 4; ++r) {
        int row = m0 + wm * 64 + m * 16 + g * 4 + r;
        float v = (acc[m][n][r] + bv) * scale;
        if (MODE == 0) {
          int b = row >> 11, si = row & (Sc - 1);
          int h = col >> 7, d = col & (HDc - 1);
          ((u16*)outp)[((size_t)((b * Hc + h) * Sc + si)) * HDc + d] = f2bf(v);
        } else {
          ((float*)outp)[(size_t)row * Dc + col] = v;
        }
      }
    }
}

// ---------------- bf16 MFMA flash attention (v2) ----------------
// grid (S/64, B*H), 256 thr = 4 waves; wave owns 16 q-rows.
// K [B,H,S,HD] and VT [B,H,HD,S] staged via global_load_lds with
// pre-swizzled SOURCE addresses (LDS dest linear). No-max softmax.
__global__ __launch_bounds__(256) void attn_mfma(
    const u16* __restrict__ Q, const u16* __restrict__ K,
    const u16* __restrict__ VT, const float* __restrict__ mask,
    u16* __restrict__ outb) {
  __shared__ u16 Ks[64 * 128];    // [k][d-units swizzled (cu&8)|((cu^k)&7)]
  __shared__ u16 Vt[128 * 64];    // [d][k-units swizzled cu^(d&7)]
  __shared__ u16 Ps[4][16 * 64];  // per-wave P [q][k-units swizzled]
  char* Ksb = (char*)Ks;
  char* Vtb = (char*)Vt;
  const int t = threadIdx.x, w = t >> 6, lane = t & 63, g = lane >> 4, c = lane & 15;
  const int bh = blockIdx.y, bq = bh >> 4, h = bh & 15;
  const int q0 = blockIdx.x * 64;
  const u16* Qp = Q + ((size_t)bh << 18);
  const u16* Kp = K + ((size_t)bh << 18);
  const u16* VTp = VT + ((size_t)bh << 18);
  char* Psb = (char*)Ps[w];

  // Q fragments (q pre-scaled by 1/sqrt(HD) in the Q-GEMM)
  bf16x8 qf[4];
  {
    int qr = q0 + w * 16 + c;
#pragma unroll
    for (int d0 = 0; d0 < 4; ++d0)
      qf[d0] = *(const bf16x8*)(Qp + (size_t)qr * HDc + d0 * 32 + g * 8);
  }

  f32x4 po[8];                       // O^T acc: d = m*16+g*4+r, q = c
#pragma unroll
  for (int m = 0; m < 8; ++m) po[m] = 0.f;
  float lsum[4] = {0.f, 0.f, 0.f, 0.f};

  const float* mbase = mask + ((size_t)bq * Sc + q0 + w * 16) * Sc;

  for (int kt = 0; kt < Sc / 64; ++kt) {
    const int k0 = kt * 64;
    // stage K: 1024 16B-units, source pre-swizzled, LDS linear
#pragma unroll
    for (int i = 0; i < 4; ++i) {
      int u = i * 256 + t, row = u >> 4, p = u & 15;
      int cu = (p & 8) | ((p ^ row) & 7);
      gload16(Kp + (size_t)(k0 + row) * HDc + cu * 8,
              Ksb + (i * 256 + (t & 192)) * 16);
    }
    // stage V^T: 1024 16B-units
#pragma unroll
    for (int i = 0; i < 4; ++i) {
      int u = i * 256 + t, d = u >> 3, p = u & 7;
      int cu = (p ^ d) & 7;
      gload16(VTp + (size_t)d * Sc + k0 + cu * 8,
              Vtb + (1024 * 16) * 0 + (i * 256 + (t & 192)) * 16);
    }
    // prefetch mask tile values for this wave's fragment slots
    float mv[4][4];
#pragma unroll
    for (int r = 0; r < 4; ++r)
#pragma unroll
      for (int n = 0; n < 4; ++n)
        mv[r][n] = mbase[(size_t)(g * 4 + r) * Sc + k0 + n * 16 + c];
    __syncthreads();

    // QK^T: S[q 16][k 64] per wave
    f32x4 sfr[4];
#pragma unroll
    for (int n = 0; n < 4; ++n) sfr[n] = 0.f;
    __builtin_amdgcn_s_setprio(1);
#pragma unroll
    for (int ds = 0; ds < 4; ++ds)
#pragma unroll
      for (int n = 0; n < 4; ++n) {
        int row = n * 16 + c;
        int cu = ds * 4 + g;
        int scu = (cu & 8) | ((cu ^ row) & 7);
        bf16x8 kf = *(const bf16x8*)(Ksb + row * 256 + scu * 16);
        sfr[n] = __builtin_amdgcn_mfma_f32_16x16x32_bf16(qf[ds], kf, sfr[n], 0, 0, 0);
      }
    __builtin_amdgcn_s_setprio(0);

    // no-max softmax: P = exp(s + mask); per-lane partial row sums
#pragma unroll
    for (int r = 0; r < 4; ++r) {
      const int qr = g * 4 + r;
#pragma unroll
      for (int n = 0; n < 4; ++n) {
        float p = __expf(sfr[n][r] + mv[r][n]);
        lsum[r] += p;
        int col = n * 16 + c;
        int scu = (col >> 3) ^ (qr & 7);
        *(u16*)(Psb + qr * 128 + scu * 16 + (col & 7) * 2) = f2bf(p);
      }
    }

    // PV: O^T += V^T * P^T
    __builtin_amdgcn_s_setprio(1);
#pragma unroll
    for (int s2 = 0; s2 < 2; ++s2) {
      int cuP = s2 * 4 + g;
      bf16x8 pf = *(const bf16x8*)(Psb + c * 128 + ((cuP ^ (c & 7)) & 7) * 16 + (cuP & 8) * 16);
#pragma unroll
      for (int m = 0; m < 8; ++m) {
        int d = m * 16 + c;
        int scuv = ((s2 * 4 + g) ^ (d & 7)) & 7;
        bf16x8 vf = *(const bf16x8*)(Vtb + d * 128 + scuv * 16);
        po[m] = __builtin_amdgcn_mfma_f32_16x16x32_bf16(vf, pf, po[m], 0, 0, 0);
      }
    }
    __builtin_amdgcn_s_setprio(0);
    __syncthreads();
  }

  // final l reduction over the 16 c-lanes of each g-group
#pragma unroll
  for (int r = 0; r < 4; ++r) {
#pragma unroll
    for (int off = 1; off < 16; off <<= 1)
      lsum[r] += __shfl_xor(lsum[r], off, 64);
  }
  float rv[4];
#pragma unroll
  for (int r = 0; r < 4; ++r) rv[r] = 1.0f / lsum[r];
  // route 1/l to the q=c lanes
  float bv0 = __shfl(rv[0], (c >> 2) * 16, 64);
  float bv1 = __shfl(rv[1], (c >> 2) * 16, 64);
  float bv2 = __shfl(rv[2], (c >> 2) * 16, 64);
  float bv3 = __shfl(rv[3], (c >> 2) * 16, 64);
  float y0 = ((c & 3) == 1) ? bv1 : bv0;
  float y1 = ((c & 3) == 3) ? bv3 : bv2;
  float rlq = ((c & 3) >= 2) ? y1 : y0;
  int qg = q0 + w * 16 + c;
#pragma unroll
  for (int m = 0; m < 8; ++m)
#pragma unroll
    for (int r = 0; r < 4; ++r) {
      int d = m * 16 + g * 4 + r;
      outb[((size_t)(bq * Sc + qg)) * Dc + h * HDc + d] = f2bf(po[m][r] * rlq);
    }
}

// ---------------- launch ----------------
extern "C" void kernel_launch(void* const* d_in, const int* in_sizes, int n_in,
                              void* d_out, int out_size, void* d_ws,
                              size_t ws_size, hipStream_t stream) {
  const float* hs   = (const float*)d_in[0];
  const float* mask = (const float*)d_in[1];
  const float* Wq   = (const float*)d_in[2];
  const float* bqp  = (const float*)d_in[3];
  const float* Wk   = (const float*)d_in[4];
  const float* bkp  = (const float*)d_in[5];
  const float* Wv   = (const float*)d_in[6];
  const float* bvp  = (const float*)d_in[7];
  const float* Wo   = (const float*)d_in[8];
  const float* bop  = (const float*)d_in[9];

  u16* Xb  = (u16*)d_ws;                 // [4096][2048] bf16
  u16* Wqb = Xb + (size_t)Mc * Dc;
  u16* Wkb = Wqb + (size_t)Dc * Dc;
  u16* Wvb = Wkb + (size_t)Dc * Dc;
  u16* Wob = Wvb + (size_t)Dc * Dc;
  u16* qb  = Wob + (size_t)Dc * Dc;      // [B,H,S,HD] bf16 (pre-scaled)
  u16* kb  = qb + (size_t)Mc * Dc;       // [B,H,S,HD] bf16
  u16* vtb = kb + (size_t)Mc * Dc;       // [B,H,HD,S] bf16
  u16* ab  = vtb + (size_t)Mc * Dc;      // [B,S,D] bf16

  const int nh4 = Mc * Dc / 4;
  const int nw4 = Dc * Dc / 4;
  cvt5<<<dim3((nh4 + 4 * nw4) / 256), dim3(256), 0, stream>>>(
      hs, Xb, nh4, Wq, Wqb, nw4, Wk, Wkb, nw4, Wv, Wvb, nw4, Wo, Wob, nw4);

  dim3 blk(256);
  dim3 gg(Dc / GBN, Mc / GBM);           // (16, 32)
  gemm_bf16<0><<<gg, blk, 0, stream>>>(Xb, Wqb, bqp, qb, SCALE);
  gemm_bf16<0><<<gg, blk, 0, stream>>>(Xb, Wkb, bkp, kb, 1.0f);
  gemm_bf16<2><<<gg, blk, 0, stream>>>(Xb, Wvb, bvp, vtb, 1.0f);
  attn_mfma<<<dim3(Sc / 64, Bc * Hc), blk, 0, stream>>>(qb, kb, vtb, mask, ab);
  gemm_bf16<1><<<gg, blk, 0, stream>>>(ab, Wob, bop, d_out, 1.0f);
}